// Round 1
// baseline (941.502 us; speedup 1.0000x reference)
//
#include <hip/hip_runtime.h>

// out = per_atom_energy (must re-init every call; harness poisons d_out)
__global__ __launch_bounds__(256) void init_out_kernel(
    const float* __restrict__ pae, float* __restrict__ out, int N)
{
    int i = blockIdx.x * blockDim.x + threadIdx.x;
    if (i < N) out[i] = pae[i];
}

// One edge per thread: e = (l0/r)^12 * l0 / 24 * poly_cutoff(r); atomicAdd to out[center]
__global__ __launch_bounds__(256) void edge_kernel(
    const float* __restrict__ edge_length,
    const int*   __restrict__ edge_center,
    const int*   __restrict__ edge_neighbor,
    const int*   __restrict__ species,
    const float* __restrict__ scales,
    float* __restrict__ out,
    int E, int T)
{
    int i = blockIdx.x * blockDim.x + threadIdx.x;
    if (i >= E) return;

    float r = edge_length[i];
    int   c = edge_center[i];
    int   n = edge_neighbor[i];

    // x = r / 6; cutoff = 1 - 28 x^6 + 48 x^7 - 21 x^8   (p=6)
    float x = r * (1.0f / 6.0f);
    if (x < 1.0f) {
        int cs = species[c];
        int ns = species[n];
        float l0 = scales[cs * T + ns];

        float x2 = x * x;
        float x3 = x2 * x;
        float x6 = x3 * x3;
        float cut = fmaf(x6, fmaf(x, fmaf(x, -21.0f, 48.0f), -28.0f), 1.0f);

        // (r/l0)^(-12) / 24 * l0 = (l0/r)^12 * l0 / 24
        float inv   = l0 / r;
        float inv2  = inv * inv;
        float inv4  = inv2 * inv2;
        float inv12 = inv4 * inv4 * inv4;

        float e = inv12 * l0 * (1.0f / 24.0f) * cut;
        atomicAdd(&out[c], e);
    }
    // x >= 1 contributes exactly 0 — skip the atomic entirely
}

extern "C" void kernel_launch(void* const* d_in, const int* in_sizes, int n_in,
                              void* d_out, int out_size, void* d_ws, size_t ws_size,
                              hipStream_t stream) {
    const float* edge_length = (const float*)d_in[0];
    const int*   edge_index  = (const int*)  d_in[1];  // (2,E) flat: [0:E)=center, [E:2E)=neighbor
    const int*   species     = (const int*)  d_in[2];  // (N,1)
    const float* pae         = (const float*)d_in[3];  // (N,1)
    const float* scales      = (const float*)d_in[4];  // (T,T)
    float*       out         = (float*)d_out;          // (N,1) float32

    const int E = in_sizes[0];
    const int N = in_sizes[3];
    int T = 1;
    while (T * T < in_sizes[4]) ++T;   // T = sqrt(len(per_edge_scales)) = 5

    init_out_kernel<<<(N + 255) / 256, 256, 0, stream>>>(pae, out, N);
    edge_kernel<<<(E + 255) / 256, 256, 0, stream>>>(
        edge_length, edge_index, edge_index + E, species, scales, out, E, T);
}